// Round 5
// baseline (80.724 us; speedup 1.0000x reference)
//
#include <hip/hip_runtime.h>

#define MEMN 262144
#define DIM 128
#define BS 256
#define NPOS 8
#define NNEG 1024
#define KTOT 1033                  /* 1 + NPOS + NNEG */
#define SORTN 2048                 /* bitonic pad */
#define LSTRIDE 1040               /* padded sorted-list stride (u32s) */
#define NCHUNK 8
#define CHUNKK 130                 /* ceil(1033/8) */
#define R 8

/* ---- sort kernel: per batch row, sort (idx<<11 | k) ascending ---- */
__global__ __launch_bounds__(256) void sort_kernel(
    const int* __restrict__ y, const int* __restrict__ pos,
    const int* __restrict__ neg, unsigned* __restrict__ sorted)
{
    const int b = blockIdx.x;
    __shared__ unsigned s[SORTN];

    for (int k = threadIdx.x; k < SORTN; k += 256) {
        unsigned v = 0xFFFFFFFFu;
        if (k < KTOT) {
            int idx;
            if (k == 0)          idx = y[b];
            else if (k <= NPOS)  idx = pos[b * NPOS + (k - 1)];
            else                 idx = neg[b * NNEG + (k - 1 - NPOS)];
            v = ((unsigned)idx << 11) | (unsigned)k;
        }
        s[k] = v;
    }

    for (unsigned size = 2; size <= SORTN; size <<= 1) {
        for (unsigned stride = size >> 1; stride > 0; stride >>= 1) {
            __syncthreads();
            for (unsigned t = threadIdx.x; t < SORTN / 2; t += 256) {
                unsigned i = 2 * t - (t & (stride - 1));
                unsigned j = i + stride;
                bool dir = ((i & size) == 0);
                unsigned a = s[i], c = s[j];
                if ((a > c) == dir) { s[i] = c; s[j] = a; }
            }
        }
    }
    __syncthreads();
    for (int t = threadIdx.x; t < KTOT; t += 256)
        sorted[(size_t)b * LSTRIDE + t] = s[t];
}

/* ---- gather kernel: R2 structure, indices from sorted list ---- */
__global__ __launch_bounds__(256) void gather_kernel(
    const float* __restrict__ video, const float* __restrict__ audio,
    const float* __restrict__ view1, const float* __restrict__ view2,
    const unsigned* __restrict__ sorted, float* __restrict__ out)
{
    const int bid   = blockIdx.x;          // c-major: all blocks of chunk c first
    const int chunk = bid >> 9;            // 0..7
    const int r     = bid & 511;
    const int m     = r >> 8;              // 0: v2a (q=video, mem=view2); 1: a2v
    const int b     = r & 255;

    const float* q_src = (m == 0) ? (video + b * DIM) : (audio + b * DIM);
    const float* memt  = (m == 0) ? view2 : view1;

    const int k0  = chunk * CHUNKK;
    const int cnt = (KTOT - k0 < CHUNKK) ? (KTOT - k0) : CHUNKK;

    __shared__ unsigned s_e[CHUNKK];
    if ((int)threadIdx.x < cnt)
        s_e[threadIdx.x] = sorted[(size_t)b * LSTRIDE + k0 + threadIdx.x];

    const int g   = threadIdx.x & 15;
    const int grp = threadIdx.x >> 4;

    float4 q0 = *(const float4*)(q_src + g * 8);
    float4 q1 = *(const float4*)(q_src + g * 8 + 4);
    float qq = q0.x*q0.x + q0.y*q0.y + q0.z*q0.z + q0.w*q0.w
             + q1.x*q1.x + q1.y*q1.y + q1.z*q1.z + q1.w*q1.w;
    qq += __shfl_xor(qq, 1);
    qq += __shfl_xor(qq, 2);
    qq += __shfl_xor(qq, 4);
    qq += __shfl_xor(qq, 8);
    const float scale = (1.0f / 0.07f) / fmaxf(sqrtf(qq), 1e-12f);
    q0.x *= scale; q0.y *= scale; q0.z *= scale; q0.w *= scale;
    q1.x *= scale; q1.y *= scale; q1.z *= scale; q1.w *= scale;

    __syncthreads();

    float* outm = out + (size_t)m * BS * KTOT + (size_t)b * KTOT;

    unsigned ent[R];
    const float* rowp[R];
#pragma unroll
    for (int i = 0; i < R; ++i) {
        int kk = grp + i * 16;
        int kc = (kk < cnt) ? kk : (cnt - 1);
        ent[i] = s_e[kc];
        rowp[i] = memt + (size_t)(ent[i] >> 11) * DIM + g * 8;
    }
    float4 r0[R], r1[R];
#pragma unroll
    for (int i = 0; i < R; ++i) {
        r0[i] = *(const float4*)(rowp[i]);
        r1[i] = *(const float4*)(rowp[i] + 4);
    }
#pragma unroll
    for (int i = 0; i < R; ++i) {
        float s = q0.x*r0[i].x + q0.y*r0[i].y + q0.z*r0[i].z + q0.w*r0[i].w
                + q1.x*r1[i].x + q1.y*r1[i].y + q1.z*r1[i].z + q1.w*r1[i].w;
        s += __shfl_xor(s, 1);
        s += __shfl_xor(s, 2);
        s += __shfl_xor(s, 4);
        s += __shfl_xor(s, 8);
        if (g == 0 && grp + i * 16 < cnt) outm[ent[i] & 2047u] = s;
    }
    for (int kk = grp + R * 16; kk < cnt; kk += 16) {   // cnt=130: grp 0,1
        unsigned e = s_e[kk];
        const float* row = memt + (size_t)(e >> 11) * DIM + g * 8;
        float4 a0 = *(const float4*)(row);
        float4 a1 = *(const float4*)(row + 4);
        float s = q0.x*a0.x + q0.y*a0.y + q0.z*a0.z + q0.w*a0.w
                + q1.x*a1.x + q1.y*a1.y + q1.z*a1.z + q1.w*a1.w;
        s += __shfl_xor(s, 1);
        s += __shfl_xor(s, 2);
        s += __shfl_xor(s, 4);
        s += __shfl_xor(s, 8);
        if (g == 0) outm[e & 2047u] = s;
    }
}

extern "C" void kernel_launch(void* const* d_in, const int* in_sizes, int n_in,
                              void* d_out, int out_size, void* d_ws, size_t ws_size,
                              hipStream_t stream) {
    const float* video = (const float*)d_in[0];
    const float* audio = (const float*)d_in[1];
    const float* view1 = (const float*)d_in[2];
    const float* view2 = (const float*)d_in[3];
    const int*   y     = (const int*)d_in[4];
    const int*   pos   = (const int*)d_in[5];
    const int*   neg   = (const int*)d_in[6];
    float* out = (float*)d_out;
    unsigned* sorted = (unsigned*)d_ws;    /* 256*1040*4 = 1.06 MB */

    sort_kernel<<<BS, 256, 0, stream>>>(y, pos, neg, sorted);
    gather_kernel<<<2 * BS * NCHUNK, 256, 0, stream>>>(video, audio, view1, view2,
                                                       sorted, out);
}

// Round 6
// 44.452 us; speedup vs baseline: 1.8160x; 1.8160x over previous
//
#include <hip/hip_runtime.h>

#define MEMN 262144
#define DIM 128
#define BS 256
#define NPOS 8
#define NNEG 1024
#define KTOT (1 + NPOS + NNEG)                 /* 1033 */
#define NCHUNK 8
#define CHUNKK ((KTOT + NCHUNK - 1) / NCHUNK)  /* 130 */
#define R 8                                    /* rows in flight per 16-lane group */

__global__ __launch_bounds__(256) void avid_sim_kernel(
    const float* __restrict__ video, const float* __restrict__ audio,
    const float* __restrict__ view1, const float* __restrict__ view2,
    const int* __restrict__ y, const int* __restrict__ pos,
    const int* __restrict__ neg, float* __restrict__ out)
{
    const int bid   = blockIdx.x;
    const int m     = bid / (BS * NCHUNK);      // 0: v2a (q=video, mem=view2); 1: a2v
    const int rem   = bid - m * (BS * NCHUNK);
    const int b     = rem / NCHUNK;
    const int chunk = rem - b * NCHUNK;

    const float* q_src = (m == 0) ? (video + b * DIM) : (audio + b * DIM);
    const float* mem   = (m == 0) ? view2 : view1;

    const int k0  = chunk * CHUNKK;
    const int cnt = (KTOT - k0 < CHUNKK) ? (KTOT - k0) : CHUNKK;

    // ---- stage this chunk's indices into LDS (one coalesced pass) ----
    __shared__ int s_idx[CHUNKK];
    if ((int)threadIdx.x < cnt) {
        const int k = k0 + (int)threadIdx.x;
        int idx;
        if (k == 0)          idx = y[b];
        else if (k <= NPOS)  idx = pos[b * NPOS + (k - 1)];
        else                 idx = neg[b * NNEG + (k - 1 - NPOS)];
        s_idx[threadIdx.x] = idx;
    }

    const int g   = threadIdx.x & 15;   // lane within 16-lane group
    const int grp = threadIdx.x >> 4;   // 16 groups

    // ---- query fragment + fused L2 normalization ----
    float4 q0 = *(const float4*)(q_src + g * 8);
    float4 q1 = *(const float4*)(q_src + g * 8 + 4);
    float qq = q0.x*q0.x + q0.y*q0.y + q0.z*q0.z + q0.w*q0.w
             + q1.x*q1.x + q1.y*q1.y + q1.z*q1.z + q1.w*q1.w;
    qq += __shfl_xor(qq, 1);
    qq += __shfl_xor(qq, 2);
    qq += __shfl_xor(qq, 4);
    qq += __shfl_xor(qq, 8);
    const float scale = (1.0f / 0.07f) / fmaxf(sqrtf(qq), 1e-12f);
    q0.x *= scale; q0.y *= scale; q0.z *= scale; q0.w *= scale;
    q1.x *= scale; q1.y *= scale; q1.z *= scale; q1.w *= scale;

    __syncthreads();

    float* outm = out + (size_t)m * BS * KTOT + (size_t)b * KTOT + k0;

    // ---- main: R rows per group in flight ----
    int kloc[R];
    const float* rowp[R];
#pragma unroll
    for (int i = 0; i < R; ++i) {
        int k = grp + i * 16;
        kloc[i] = k;
        int kc = (k < cnt) ? k : (cnt - 1);     // clamp: harmless dup load, no store
        rowp[i] = mem + (size_t)s_idx[kc] * DIM + g * 8;
    }
    float4 r0[R], r1[R];
#pragma unroll
    for (int i = 0; i < R; ++i) {               // 2R independent 16B loads in flight
        r0[i] = *(const float4*)(rowp[i]);
        r1[i] = *(const float4*)(rowp[i] + 4);
    }
#pragma unroll
    for (int i = 0; i < R; ++i) {
        float s = q0.x*r0[i].x + q0.y*r0[i].y + q0.z*r0[i].z + q0.w*r0[i].w
                + q1.x*r1[i].x + q1.y*r1[i].y + q1.z*r1[i].z + q1.w*r1[i].w;
        s += __shfl_xor(s, 1);
        s += __shfl_xor(s, 2);
        s += __shfl_xor(s, 4);
        s += __shfl_xor(s, 8);
        if (g == 0 && kloc[i] < cnt) outm[kloc[i]] = s;
    }
    // remainder rows (only when cnt > R*16, i.e. cnt=130 -> groups 0,1)
    for (int k = grp + R * 16; k < cnt; k += 16) {
        const float* row = mem + (size_t)s_idx[k] * DIM + g * 8;
        float4 a0 = *(const float4*)(row);
        float4 a1 = *(const float4*)(row + 4);
        float s = q0.x*a0.x + q0.y*a0.y + q0.z*a0.z + q0.w*a0.w
                + q1.x*a1.x + q1.y*a1.y + q1.z*a1.z + q1.w*a1.w;
        s += __shfl_xor(s, 1);
        s += __shfl_xor(s, 2);
        s += __shfl_xor(s, 4);
        s += __shfl_xor(s, 8);
        if (g == 0) outm[k] = s;
    }
}

extern "C" void kernel_launch(void* const* d_in, const int* in_sizes, int n_in,
                              void* d_out, int out_size, void* d_ws, size_t ws_size,
                              hipStream_t stream) {
    const float* video = (const float*)d_in[0];
    const float* audio = (const float*)d_in[1];
    const float* view1 = (const float*)d_in[2];
    const float* view2 = (const float*)d_in[3];
    const int*   y     = (const int*)d_in[4];
    const int*   pos   = (const int*)d_in[5];
    const int*   neg   = (const int*)d_in[6];
    float* out = (float*)d_out;

    dim3 grid(2 * BS * NCHUNK);
    dim3 block(256);
    avid_sim_kernel<<<grid, block, 0, stream>>>(video, audio, view1, view2,
                                                y, pos, neg, out);
}